// Round 11
// baseline (204.869 us; speedup 1.0000x reference)
//
#include <hip/hip_runtime.h>
#include <math.h>

// Problem constants (fixed by setup_inputs)
#define NB     128
#define NNODE  64
#define NTOT   8192
#define DIM    64
#define PSTR   136     // padded k-stride (bf16 elems) for Ptb / w2x rows
#define WS72   72      // padded k-stride for small 64-k weight transposes

typedef __bf16 bf16x8 __attribute__((ext_vector_type(8)));
typedef float  f32x4  __attribute__((ext_vector_type(4)));

__device__ __forceinline__ float frcp(float x) {
    return __builtin_amdgcn_rcpf(x);
}

__device__ __forceinline__ float silu_f(float x) {
    return x * frcp(1.0f + __expf(-x));
}

__device__ __forceinline__ unsigned short bf16bits(float f) {
    return __builtin_bit_cast(unsigned short, (__bf16)f);
}

__device__ __forceinline__ bf16x8 to_bf16x8(const float* v) {
    bf16x8 o;
    #pragma unroll
    for (int j = 0; j < 8; ++j) o[j] = (__bf16)v[j];
    return o;
}

__device__ __forceinline__ float wsum(float v) {
    #pragma unroll
    for (int m = 1; m < 64; m <<= 1) v += __shfl_xor(v, m, 64);
    return v;
}

// ---- DPP reduction helpers (VALU pipe; no LDS) ----
template<int CTRL>
__device__ __forceinline__ float dpp_add(float v) {
    const int r = __builtin_amdgcn_update_dpp(
        0, __builtin_bit_cast(int, v), CTRL, 0xF, 0xF, true);
    return v + __builtin_bit_cast(float, r);
}
template<int CTRL>
__device__ __forceinline__ float dpp_max(float v) {
    const int r = __builtin_amdgcn_update_dpp(
        __builtin_bit_cast(int, -1e30f), __builtin_bit_cast(int, v),
        CTRL, 0xF, 0xF, false);
    return fmaxf(v, __builtin_bit_cast(float, r));
}
// 16-lane sum: total lands in lane m=15 of each 16-group
__device__ __forceinline__ float row_sum16(float v) {
    v = dpp_add<0x111>(v);
    v = dpp_add<0x112>(v);
    v = dpp_add<0x114>(v);
    v = dpp_add<0x118>(v);
    return v;
}
// full 64-lane sum/max: valid in lane 63
__device__ __forceinline__ float wave_sum_dpp(float v) {
    v = row_sum16(v);
    v = dpp_add<0x142>(v);   // row_bcast15
    v = dpp_add<0x143>(v);   // row_bcast31
    return v;
}
__device__ __forceinline__ float wave_max_dpp(float v) {
    v = dpp_max<0x111>(v);
    v = dpp_max<0x112>(v);
    v = dpp_max<0x114>(v);
    v = dpp_max<0x118>(v);
    v = dpp_max<0x142>(v);
    v = dpp_max<0x143>(v);
    return v;
}
__device__ __forceinline__ float readlane63(float v) {
    return __builtin_bit_cast(float,
        __builtin_amdgcn_readlane(__builtin_bit_cast(int, v), 63));
}
// broadcast lane 15 of each 16-group to all 16 lanes
__device__ __forceinline__ float bcast15(float v) {
    return __builtin_bit_cast(float,
        __builtin_amdgcn_ds_swizzle(__builtin_bit_cast(int, v), 0x01F0));
}

// ---------------------------------------------------------------------------
// K0: prep transposed bf16 weights + xnorm. grid 128 x 256.
// ---------------------------------------------------------------------------
__global__ __launch_bounds__(256) void k0_prep(
        const float* __restrict__ kvw2, const float* __restrict__ phxw1,
        const float* __restrict__ X, const float* __restrict__ xw,
        const float* __restrict__ qw1, const float* __restrict__ qw2,
        const float* __restrict__ kvw1,
        const float* __restrict__ phh1, const float* __restrict__ phh2,
        unsigned short* __restrict__ w2x, float* __restrict__ Xn4,
        unsigned short* __restrict__ qw1T, unsigned short* __restrict__ qw2T,
        unsigned short* __restrict__ kvw1T,
        unsigned short* __restrict__ phh1T, unsigned short* __restrict__ phh2T) {
    const int k = blockIdx.x;       // 0..127 : k-index and batch id
    const int T = threadIdx.x;
    if (T < 128) {
        w2x[T*PSTR + k] = bf16bits(kvw2[k*128 + T]);
    } else if (T < 192) {
        const int n2 = T - 128;
        float acc = 0.f;
        #pragma unroll 8
        for (int j = 0; j < 64; ++j)
            acc += kvw2[k*128 + 64 + j] * phxw1[j*64 + n2];
        w2x[(128 + n2)*PSTR + k] = bf16bits(acc);
    } else {
        const int L = T - 192;      // wave 3: xnorm for batch k
        const int n = k*64 + L;
        const float x0 = X[n*3+0], x1 = X[n*3+1], x2 = X[n*3+2];
        const float nm = sqrtf(x0*x0 + x1*x1 + x2*x2);
        const float mean = wsum(nm) * (1.0f/64.0f);
        const float sc = xw[0] * frcp(mean + 1e-5f);
        float4 o; o.x = x0*sc; o.y = x1*sc; o.z = x2*sc; o.w = 0.f;
        *(float4*)&Xn4[n*4] = o;
    }
    if (k < 64) {
        if (T < 128) kvw1T[T*WS72 + k] = bf16bits(kvw1[(1+k)*128 + T]);
    } else {
        const int kk = k - 64;
        if (T < 64)       qw1T[T*WS72 + kk]        = bf16bits(qw1[kk*64 + T]);
        else if (T < 128) qw2T[(T-64)*WS72 + kk]   = bf16bits(qw2[kk*64 + (T-64)]);
        else if (T < 192) phh1T[(T-128)*WS72 + kk] = bf16bits(phh1[kk*64 + (T-128)]);
        else              phh2T[(T-192)*WS72 + kk] = bf16bits(phh2[kk*64 + (T-192)]);
    }
}

// ---------------------------------------------------------------------------
// K2 (MFMA): single-wave 16-node tiles, role-split blocks. grid 1024 x 64.
// ---------------------------------------------------------------------------
__global__ __launch_bounds__(64) void k2_node(
        const float* __restrict__ H,
        const unsigned short* __restrict__ wbase,   // qw1T|qw2T|kvw1T
        const float* __restrict__ qnw, const float* __restrict__ qnb,
        float* __restrict__ Qn, unsigned short* __restrict__ Ptb) {
    const int tile = blockIdx.x >> 1, role = blockIdx.x & 1;
    const int nb = tile * 16;
    const int L = threadIdx.x, q = L >> 4, m = L & 15;
    __shared__ __align__(16) unsigned short zb[16*WS72];

    bf16x8 hf[2];
    #pragma unroll
    for (int ks = 0; ks < 2; ++ks) {
        float v[8];
        *(float4*)&v[0] = *(const float4*)&H[(size_t)(nb + m)*64 + ks*32 + q*8];
        *(float4*)&v[4] = *(const float4*)&H[(size_t)(nb + m)*64 + ks*32 + q*8 + 4];
        hf[ks] = to_bf16x8(v);
    }

    f32x4 acc[4];
    if (role == 1) {
        const unsigned short* kvw1T = wbase + 128*WS72;
        #pragma unroll
        for (int ph = 0; ph < 2; ++ph) {
            #pragma unroll
            for (int ct = 0; ct < 4; ++ct) acc[ct] = (f32x4){0.f,0.f,0.f,0.f};
            #pragma unroll
            for (int ks = 0; ks < 2; ++ks)
                #pragma unroll
                for (int ct = 0; ct < 4; ++ct) {
                    const bf16x8 b = *(const bf16x8*)&kvw1T[(ph*64 + ct*16 + m)*WS72 + ks*32 + q*8];
                    acc[ct] = __builtin_amdgcn_mfma_f32_16x16x32_bf16(hf[ks], b, acc[ct], 0, 0, 0);
                }
            #pragma unroll
            for (int ct = 0; ct < 4; ++ct)
                #pragma unroll
                for (int r = 0; r < 4; ++r)
                    Ptb[(size_t)(nb + q*4 + r)*PSTR + ph*64 + ct*16 + m]
                        = bf16bits(acc[ct][r]);
        }
        return;
    }

    // role 0: GEMM1 Z = silu(H@qw1)
    #pragma unroll
    for (int ct = 0; ct < 4; ++ct) acc[ct] = (f32x4){0.f,0.f,0.f,0.f};
    #pragma unroll
    for (int ks = 0; ks < 2; ++ks)
        #pragma unroll
        for (int ct = 0; ct < 4; ++ct) {
            const bf16x8 b = *(const bf16x8*)&wbase[(ct*16 + m)*WS72 + ks*32 + q*8];
            acc[ct] = __builtin_amdgcn_mfma_f32_16x16x32_bf16(hf[ks], b, acc[ct], 0, 0, 0);
        }
    #pragma unroll
    for (int ct = 0; ct < 4; ++ct)
        #pragma unroll
        for (int r = 0; r < 4; ++r)
            zb[(q*4 + r)*WS72 + ct*16 + m] = bf16bits(silu_f(acc[ct][r]));

    bf16x8 zf[2];
    #pragma unroll
    for (int ks = 0; ks < 2; ++ks)
        zf[ks] = *(const bf16x8*)&zb[m*WS72 + ks*32 + q*8];
    const unsigned short* qw2T = wbase + 64*WS72;
    #pragma unroll
    for (int ct = 0; ct < 4; ++ct) acc[ct] = (f32x4){0.f,0.f,0.f,0.f};
    #pragma unroll
    for (int ks = 0; ks < 2; ++ks)
        #pragma unroll
        for (int ct = 0; ct < 4; ++ct) {
            const bf16x8 b = *(const bf16x8*)&qw2T[(ct*16 + m)*WS72 + ks*32 + q*8];
            acc[ct] = __builtin_amdgcn_mfma_f32_16x16x32_bf16(zf[ks], b, acc[ct], 0, 0, 0);
        }
    float qnwv[4], qnbv[4];
    #pragma unroll
    for (int ct = 0; ct < 4; ++ct) { qnwv[ct] = qnw[ct*16+m]; qnbv[ct] = qnb[ct*16+m]; }
    #pragma unroll
    for (int r = 0; r < 4; ++r) {
        float s1 = 0.f, s2 = 0.f;
        #pragma unroll
        for (int ct = 0; ct < 4; ++ct) {
            const float z = acc[ct][r];
            s1 += z; s2 = fmaf(z, z, s2);
        }
        #pragma unroll
        for (int sh = 1; sh < 16; sh <<= 1) {
            s1 += __shfl_xor(s1, sh, 64);
            s2 += __shfl_xor(s2, sh, 64);
        }
        const float mu = s1 * (1.0f/64.0f);
        const float rstd = rsqrtf(s2 * (1.0f/64.0f) - mu*mu + 1e-5f);
        const int row = nb + q*4 + r;
        #pragma unroll
        for (int ct = 0; ct < 4; ++ct)
            Qn[(size_t)row*64 + ct*16 + m] = (acc[ct][r] - mu)*rstd*qnwv[ct] + qnbv[ct];
    }
}

// ---------------------------------------------------------------------------
// K3: fused edge pipeline + H-MLP epilogue. Block = (graph, 8 dsts),
// 256 thr / 2 pairs; wave half h owns src rows [32h,32h+32).
// This round: only K-weights in LDS (17.4 KB; V+G B-frags stream from
// global L1/L2 like R9's G-pass) -> LDS ~22.5 KB; __launch_bounds__(256,5)
// = 102-reg budget, incremental V/G (no accv hoist -> no spill).
// DPP softmax + DPP epilogue kept from R10.
// ---------------------------------------------------------------------------
__global__ __launch_bounds__(256, 5) void k3_edge(
        const float* __restrict__ Xn4, const float* __restrict__ Qn,
        const unsigned short* __restrict__ Ptb,
        const unsigned short* __restrict__ w2x,
        const float* __restrict__ kvw1,
        const float* __restrict__ knw, const float* __restrict__ knb,
        const float* __restrict__ pxw2,
        const unsigned short* __restrict__ phhT,   // phh1T|phh2T
        const float* __restrict__ phb1, const float* __restrict__ phb2,
        const float* __restrict__ H,
        float* __restrict__ Hout, float* __restrict__ Xout) {
    const int bid = blockIdx.x;
    const int g = bid >> 3, dgrp = bid & 7;
    const int T = threadIdx.x, w = T >> 6, L = T & 63;
    const int q = L >> 4, m = L & 15;
    const int pair = w >> 1, half = w & 1;

    __shared__ __align__(16) unsigned short sKw[64*PSTR];   // 17408 B (K only)
    __shared__ __align__(16) float sxr[4][32][4];           // 2048 B
    __shared__ __align__(16) unsigned short sAb[8*WS72];    // 1152 B
    __shared__ float w0s[128];                              // 512 B
    __shared__ float knws[64], knbs[64], pxs[64];           // 768 B
    __shared__ float sred[2][2][2];
    __shared__ float sA[2][64];
    __shared__ float sX[2][4];

    // ---- staging (once per block) ----
    {
        const uint4* s1 = (const uint4*)w2x;
        uint4* d1 = (uint4*)sKw;
        #pragma unroll
        for (int it = 0; it < 5; ++it) {
            const int idx = T + 256*it;
            if (idx < 64*PSTR/8) d1[idx] = s1[idx];
        }
        if (T < 128) w0s[T] = kvw1[T];
        if (T < 64)            knws[T]       = knw[T];
        else if (T < 128)      knbs[T - 64]  = knb[T - 64];
        else if (T < 192)      pxs[T - 128]  = pxw2[T - 128];
    }
    __syncthreads();

    const unsigned short* PtG = Ptb + (size_t)g*64*PSTR;
    const unsigned short* Vw  = w2x + 64*PSTR;      // V-weight rows (global)
    const unsigned short* Gw  = w2x + 128*PSTR;     // G-weight rows (global)
    const float mflag = (m == 15) ? 1.0f : 0.0f;

    #pragma unroll 1
    for (int i = 0; i < 4; ++i) {
        const int dql = i*2 + pair;         // 0..7 local dst
        const int dl  = dgrp*8 + dql;       // 0..63 in-graph dst
        const int d   = g*64 + dl;

        // ---- Qn for this dst (global, L2-hot) ----
        float qdv[4];
        #pragma unroll
        for (int ct = 0; ct < 4; ++ct)
            qdv[ct] = Qn[(size_t)d*64 + ct*16 + m];

        // ---- geometry for this wave's 32 src rows ----
        if (L < 32) {
            const int row = half*32 + L;
            const float4 xs  = *(const float4*)&Xn4[(g*64 + row)*4];
            const float4 xdv = *(const float4*)&Xn4[(g*64 + dl)*4];
            const float r0 = xs.x - xdv.x, r1 = xs.y - xdv.y, r2 = xs.z - xdv.z;
            const float rd = r0*r0 + r1*r1 + r2*r2;
            const float inv = frcp(1.0f + sqrtf(rd + 1e-8f));
            float4 o; o.x = r0*inv; o.y = r1*inv; o.z = r2*inv; o.w = rd;
            *(float4*)&sxr[w][L][0] = o;
        }
        asm volatile("s_waitcnt lgkmcnt(0)" ::: "memory");

        // ---- build t A-fragments (rows half*32 + rt*16 + m) ----
        bf16x8 af[2][4];
        float rdv[2];
        #pragma unroll
        for (int rt = 0; rt < 2; ++rt) rdv[rt] = sxr[w][rt*16 + m][3];
        #pragma unroll
        for (int ks = 0; ks < 4; ++ks) {
            float w0v[8];
            *(float4*)&w0v[0] = *(const float4*)&w0s[ks*32 + q*8];
            *(float4*)&w0v[4] = *(const float4*)&w0s[ks*32 + q*8 + 4];
            #pragma unroll
            for (int rt = 0; rt < 2; ++rt) {
                const int row = half*32 + rt*16 + m;
                const bf16x8 pb = *(const bf16x8*)&PtG[(size_t)row*PSTR + ks*32 + q*8];
                bf16x8 o;
                #pragma unroll
                for (int j = 0; j < 8; ++j) {
                    const float pf = (float)pb[j];
                    o[j] = (__bf16)silu_f(fmaf(rdv[rt], w0v[j], pf));
                }
                af[rt][ks] = o;
            }
        }

        // ---- K-pass: incremental ct, LN stats accumulate (LDS weights) ----
        float qdw[4], Sqdw = 0.f, Sqdb = 0.f;
        #pragma unroll
        for (int ct = 0; ct < 4; ++ct) {
            qdw[ct] = qdv[ct] * knws[ct*16 + m];
            Sqdw += qdw[ct];
            Sqdb += qdv[ct] * knbs[ct*16 + m];
        }
        Sqdw = row_sum16(Sqdw);
        Sqdb = row_sum16(Sqdb);

        float s1a[2][4], s2a[2][4], skqa[2][4];
        #pragma unroll
        for (int rt = 0; rt < 2; ++rt)
            #pragma unroll
            for (int r = 0; r < 4; ++r) { s1a[rt][r]=0.f; s2a[rt][r]=0.f; skqa[rt][r]=0.f; }

        #pragma unroll
        for (int ct = 0; ct < 4; ++ct) {
            f32x4 acc[2];
            acc[0] = (f32x4){0.f,0.f,0.f,0.f};
            acc[1] = (f32x4){0.f,0.f,0.f,0.f};
            #pragma unroll
            for (int ks = 0; ks < 4; ++ks) {
                const bf16x8 b = *(const bf16x8*)&sKw[(ct*16 + m)*PSTR + ks*32 + q*8];
                #pragma unroll
                for (int rt = 0; rt < 2; ++rt)
                    acc[rt] = __builtin_amdgcn_mfma_f32_16x16x32_bf16(
                                  af[rt][ks], b, acc[rt], 0, 0, 0);
            }
            #pragma unroll
            for (int rt = 0; rt < 2; ++rt)
                #pragma unroll
                for (int r = 0; r < 4; ++r) {
                    const float kv = acc[rt][r];
                    s1a[rt][r] += kv;
                    s2a[rt][r] = fmaf(kv, kv, s2a[rt][r]);
                    skqa[rt][r] = fmaf(kv, qdw[ct], skqa[rt][r]);
                }
        }

        float sc[2][4];
        #pragma unroll
        for (int rt = 0; rt < 2; ++rt)
            #pragma unroll
            for (int r = 0; r < 4; ++r) {
                const float s1 = row_sum16(s1a[rt][r]);
                const float s2 = row_sum16(s2a[rt][r]);
                const float skq = row_sum16(skqa[rt][r]);
                const float mu = s1 * (1.0f/64.0f);
                const float rstd = rsqrtf(s2 * (1.0f/64.0f) - mu*mu + 1e-5f);
                float scv = (rstd * (skq - mu*Sqdw) + Sqdb) * 0.125f;
                scv = bcast15(scv);
                const int row_g = half*32 + rt*16 + q*4 + r;
                sc[rt][r] = (row_g == dl) ? -1e30f : scv;
            }

        // ---- wave-local softmax stats via DPP ----
        float mloc = -1e30f;
        #pragma unroll
        for (int rt = 0; rt < 2; ++rt)
            #pragma unroll
            for (int r = 0; r < 4; ++r) mloc = fmaxf(mloc, sc[rt][r]);
        const float smx = readlane63(wave_max_dpp(mloc));
        float e8[2][4], ssum = 0.f;
        #pragma unroll
        for (int rt = 0; rt < 2; ++rt)
            #pragma unroll
            for (int r = 0; r < 4; ++r) {
                e8[rt][r] = __expf(sc[rt][r] - smx);
                ssum += e8[rt][r];
            }
        // rows duplicated over 16 m-lanes -> Sw = 16 * true sum (folded below)
        const float Sw = readlane63(wave_sum_dpp(ssum));
        if (L == 0) { sred[pair][half][0] = smx; sred[pair][half][1] = Sw; }
        __syncthreads();                                    // b1
        float al[2][4];
        {
            const float mo = sred[pair][half^1][0];
            const float So = sred[pair][half^1][1];
            const float M  = fmaxf(smx, mo);
            const float es = __expf(smx - M);
            const float eo = __expf(mo - M);
            const float alf = 16.0f * es * frcp(Sw*es + So*eo);
            #pragma unroll
            for (int rt = 0; rt < 2; ++rt)
                #pragma unroll
                for (int r = 0; r < 4; ++r) al[rt][r] = e8[rt][r] * alf;
        }

        // ---- V-pass: incremental ct (global weights) ----
        float p[4];
        #pragma unroll
        for (int ct = 0; ct < 4; ++ct) {
            f32x4 acc[2];
            acc[0] = (f32x4){0.f,0.f,0.f,0.f};
            acc[1] = (f32x4){0.f,0.f,0.f,0.f};
            #pragma unroll
            for (int ks = 0; ks < 4; ++ks) {
                const bf16x8 b = *(const bf16x8*)&Vw[(size_t)(ct*16 + m)*PSTR + ks*32 + q*8];
                #pragma unroll
                for (int rt = 0; rt < 2; ++rt)
                    acc[rt] = __builtin_amdgcn_mfma_f32_16x16x32_bf16(
                                  af[rt][ks], b, acc[rt], 0, 0, 0);
            }
            float pv = 0.f;
            #pragma unroll
            for (int rt = 0; rt < 2; ++rt)
                #pragma unroll
                for (int r = 0; r < 4; ++r)
                    pv = fmaf(al[rt][r], acc[rt][r], pv);
            pv += __shfl_xor(pv, 16, 64);
            pv += __shfl_xor(pv, 32, 64);
            p[ct] = pv;
        }

        // ---- G-pass: incremental ct (global weights), phsum accumulate ----
        float phsum[2][4];
        #pragma unroll
        for (int rt = 0; rt < 2; ++rt)
            #pragma unroll
            for (int r = 0; r < 4; ++r) phsum[rt][r] = 0.f;
        #pragma unroll
        for (int ct = 0; ct < 4; ++ct) {
            f32x4 acc[2];
            acc[0] = (f32x4){0.f,0.f,0.f,0.f};
            acc[1] = (f32x4){0.f,0.f,0.f,0.f};
            #pragma unroll
            for (int ks = 0; ks < 4; ++ks) {
                const bf16x8 b = *(const bf16x8*)&Gw[(size_t)(ct*16 + m)*PSTR + ks*32 + q*8];
                #pragma unroll
                for (int rt = 0; rt < 2; ++rt)
                    acc[rt] = __builtin_amdgcn_mfma_f32_16x16x32_bf16(
                                  af[rt][ks], b, acc[rt], 0, 0, 0);
            }
            const float px = pxs[ct*16 + m];
            #pragma unroll
            for (int rt = 0; rt < 2; ++rt)
                #pragma unroll
                for (int r = 0; r < 4; ++r)
                    phsum[rt][r] = fmaf(silu_f(al[rt][r] * acc[rt][r]), px, phsum[rt][r]);
        }

        // ---- phx epilogue + X partial (DPP) ----
        float xa0 = 0.f, xa1 = 0.f, xa2 = 0.f;
        #pragma unroll
        for (int rt = 0; rt < 2; ++rt)
            #pragma unroll
            for (int r = 0; r < 4; ++r) {
                const float ph = row_sum16(phsum[rt][r]) * mflag;
                const float4 xr = *(const float4*)&sxr[w][rt*16 + q*4 + r][0];
                xa0 = fmaf(ph, xr.x, xa0);
                xa1 = fmaf(ph, xr.y, xa1);
                xa2 = fmaf(ph, xr.z, xa2);
            }
        xa0 = dpp_add<0x142>(xa0); xa0 = dpp_add<0x143>(xa0);
        xa1 = dpp_add<0x142>(xa1); xa1 = dpp_add<0x143>(xa1);
        xa2 = dpp_add<0x142>(xa2); xa2 = dpp_add<0x143>(xa2);

        if (half == 1) {
            if (q == 0)
                #pragma unroll
                for (int ct = 0; ct < 4; ++ct) sA[pair][ct*16 + m] = p[ct];
            if (L == 63) {
                sX[pair][0] = xa0; sX[pair][1] = xa1; sX[pair][2] = xa2;
            }
        }
        __syncthreads();                                    // b2
        if (half == 0) {
            if (q == 0)
                #pragma unroll
                for (int ct = 0; ct < 4; ++ct)
                    sAb[dql*WS72 + ct*16 + m] =
                        bf16bits(p[ct] + sA[pair][ct*16 + m]);
            if (L == 63) {
                const float4 xdv = *(const float4*)&Xn4[(g*64 + dl)*4];
                Xout[(size_t)d*3 + 0] = xdv.x + xa0 + sX[pair][0];
                Xout[(size_t)d*3 + 1] = xdv.y + xa1 + sX[pair][1];
                Xout[(size_t)d*3 + 2] = xdv.z + xa2 + sX[pair][2];
            }
        }
    }

    // ---- fused k4: H_out MLP for this block's 8 dsts (wave 0 only) ----
    __syncthreads();
    if (w == 0) {
        const int mr = m & 7;
        const size_t nbase = (size_t)g*64 + dgrp*8;

        bf16x8 uf[2];
        #pragma unroll
        for (int ks = 0; ks < 2; ++ks) {
            const bf16x8 a8 = *(const bf16x8*)&sAb[mr*WS72 + ks*32 + q*8];
            float h[8], v[8];
            *(float4*)&h[0] = *(const float4*)&H[(nbase + mr)*64 + ks*32 + q*8];
            *(float4*)&h[4] = *(const float4*)&H[(nbase + mr)*64 + ks*32 + q*8 + 4];
            #pragma unroll
            for (int j = 0; j < 8; ++j) {
                const float a = (float)a8[j];
                v[j] = a * a * h[j];
            }
            uf[ks] = to_bf16x8(v);
        }

        f32x4 acc[4];
        #pragma unroll
        for (int ct = 0; ct < 4; ++ct) acc[ct] = (f32x4){0.f,0.f,0.f,0.f};
        #pragma unroll
        for (int ks = 0; ks < 2; ++ks)
            #pragma unroll
            for (int ct = 0; ct < 4; ++ct) {
                const bf16x8 b = *(const bf16x8*)&phhT[(ct*16 + m)*WS72 + ks*32 + q*8];
                acc[ct] = __builtin_amdgcn_mfma_f32_16x16x32_bf16(uf[ks], b, acc[ct], 0, 0, 0);
            }
        #pragma unroll
        for (int ct = 0; ct < 4; ++ct) {
            const float bv = phb1[ct*16 + m];
            #pragma unroll
            for (int r = 0; r < 4; ++r)
                if (q < 2)
                    sAb[(q*4 + r)*WS72 + ct*16 + m] = bf16bits(silu_f(acc[ct][r] + bv));
        }

        bf16x8 zf[2];
        #pragma unroll
        for (int ks = 0; ks < 2; ++ks)
            zf[ks] = *(const bf16x8*)&sAb[mr*WS72 + ks*32 + q*8];
        const unsigned short* phh2T = phhT + 64*WS72;
        #pragma unroll
        for (int ct = 0; ct < 4; ++ct) acc[ct] = (f32x4){0.f,0.f,0.f,0.f};
        #pragma unroll
        for (int ks = 0; ks < 2; ++ks)
            #pragma unroll
            for (int ct = 0; ct < 4; ++ct) {
                const bf16x8 b = *(const bf16x8*)&phh2T[(ct*16 + m)*WS72 + ks*32 + q*8];
                acc[ct] = __builtin_amdgcn_mfma_f32_16x16x32_bf16(zf[ks], b, acc[ct], 0, 0, 0);
            }
        #pragma unroll
        for (int ct = 0; ct < 4; ++ct) {
            const float bv = phb2[ct*16 + m];
            #pragma unroll
            for (int r = 0; r < 4; ++r)
                if (q < 2) {
                    const size_t idx = (nbase + q*4 + r)*64 + ct*16 + m;
                    Hout[idx] = H[idx] + acc[ct][r] + bv;
                }
        }
    }
}

// ---------------------------------------------------------------------------
extern "C" void kernel_launch(void* const* d_in, const int* in_sizes, int n_in,
                              void* d_out, int out_size, void* d_ws, size_t ws_size,
                              hipStream_t stream) {
    const float* X    = (const float*)d_in[1];
    const float* H    = (const float*)d_in[2];
    const float* xw   = (const float*)d_in[4];
    const float* qw1  = (const float*)d_in[5];
    const float* qw2  = (const float*)d_in[6];
    const float* kvw1 = (const float*)d_in[7];
    const float* kvw2 = (const float*)d_in[8];
    const float* qnw  = (const float*)d_in[9];
    const float* qnb  = (const float*)d_in[10];
    const float* knw  = (const float*)d_in[11];
    const float* knb  = (const float*)d_in[12];
    const float* pxw1 = (const float*)d_in[13];
    const float* pxw2 = (const float*)d_in[14];
    const float* phw1 = (const float*)d_in[15];
    const float* phb1 = (const float*)d_in[16];
    const float* phw2 = (const float*)d_in[17];
    const float* phb2 = (const float*)d_in[18];

    float* out = (float*)d_out;
    char*  ws  = (char*)d_ws;

    size_t off = 0;
    float* Xn4 = (float*)(ws + off);          off += (size_t)NTOT*4*4;
    float* Qn  = (float*)(ws + off);          off += (size_t)NTOT*64*4;
    unsigned short* Ptb = (unsigned short*)(ws + off); off += (size_t)NTOT*PSTR*2;
    unsigned short* w2x   = (unsigned short*)(ws + off); off += (size_t)192*PSTR*2;
    // k2 weights contiguous: qw1T | qw2T | kvw1T  (256 rows x WS72)
    unsigned short* qw1T  = (unsigned short*)(ws + off); off += (size_t)64*WS72*2;
    unsigned short* qw2T  = (unsigned short*)(ws + off); off += (size_t)64*WS72*2;
    unsigned short* kvw1T = (unsigned short*)(ws + off); off += (size_t)128*WS72*2;
    // k3 H-MLP weights contiguous: phh1T | phh2T  (128 rows x WS72)
    unsigned short* phh1T = (unsigned short*)(ws + off); off += (size_t)64*WS72*2;
    unsigned short* phh2T = (unsigned short*)(ws + off); off += (size_t)64*WS72*2;

    k0_prep<<<128, 256, 0, stream>>>(kvw2, pxw1, X, xw, qw1, qw2, kvw1,
                                     phw1, phw2, w2x, Xn4,
                                     qw1T, qw2T, kvw1T, phh1T, phh2T);
    k2_node<<<1024, 64, 0, stream>>>(H, qw1T, qnw, qnb, Qn, Ptb);
    k3_edge<<<1024, 256, 0, stream>>>(Xn4, Qn, Ptb, w2x, kvw1, knw, knb,
                                      pxw2, phh1T, phb1, phb2, H,
                                      out + NTOT*3, out);
}

// Round 12
// 164.826 us; speedup vs baseline: 1.2429x; 1.2429x over previous
//
#include <hip/hip_runtime.h>
#include <math.h>

// Problem constants (fixed by setup_inputs)
#define NB     128
#define NNODE  64
#define NTOT   8192
#define DIM    64
#define PSTR   136     // padded k-stride (bf16 elems) for Ptb / w2x rows
#define WS72   72      // padded k-stride for small 64-k weight transposes

typedef __bf16 bf16x8 __attribute__((ext_vector_type(8)));
typedef float  f32x4  __attribute__((ext_vector_type(4)));

__device__ __forceinline__ float frcp(float x) {
    return __builtin_amdgcn_rcpf(x);
}

__device__ __forceinline__ float silu_f(float x) {
    return x * frcp(1.0f + __expf(-x));
}

__device__ __forceinline__ unsigned short bf16bits(float f) {
    return __builtin_bit_cast(unsigned short, (__bf16)f);
}

__device__ __forceinline__ bf16x8 to_bf16x8(const float* v) {
    bf16x8 o;
    #pragma unroll
    for (int j = 0; j < 8; ++j) o[j] = (__bf16)v[j];
    return o;
}

__device__ __forceinline__ float wsum(float v) {
    #pragma unroll
    for (int m = 1; m < 64; m <<= 1) v += __shfl_xor(v, m, 64);
    return v;
}

// ---- DPP reduction helpers (VALU pipe; no LDS) ----
template<int CTRL>
__device__ __forceinline__ float dpp_add(float v) {
    const int r = __builtin_amdgcn_update_dpp(
        0, __builtin_bit_cast(int, v), CTRL, 0xF, 0xF, true);
    return v + __builtin_bit_cast(float, r);
}
template<int CTRL>
__device__ __forceinline__ float dpp_max(float v) {
    const int r = __builtin_amdgcn_update_dpp(
        __builtin_bit_cast(int, -1e30f), __builtin_bit_cast(int, v),
        CTRL, 0xF, 0xF, false);
    return fmaxf(v, __builtin_bit_cast(float, r));
}
// 16-lane sum: total lands in lane m=15 of each 16-group
__device__ __forceinline__ float row_sum16(float v) {
    v = dpp_add<0x111>(v);
    v = dpp_add<0x112>(v);
    v = dpp_add<0x114>(v);
    v = dpp_add<0x118>(v);
    return v;
}
// full 64-lane sum/max: valid in lane 63
__device__ __forceinline__ float wave_sum_dpp(float v) {
    v = row_sum16(v);
    v = dpp_add<0x142>(v);   // row_bcast15
    v = dpp_add<0x143>(v);   // row_bcast31
    return v;
}
__device__ __forceinline__ float wave_max_dpp(float v) {
    v = dpp_max<0x111>(v);
    v = dpp_max<0x112>(v);
    v = dpp_max<0x114>(v);
    v = dpp_max<0x118>(v);
    v = dpp_max<0x142>(v);
    v = dpp_max<0x143>(v);
    return v;
}
__device__ __forceinline__ float readlane63(float v) {
    return __builtin_bit_cast(float,
        __builtin_amdgcn_readlane(__builtin_bit_cast(int, v), 63));
}
// broadcast lane 15 of each 16-group to all 16 lanes
__device__ __forceinline__ float bcast15(float v) {
    return __builtin_bit_cast(float,
        __builtin_amdgcn_ds_swizzle(__builtin_bit_cast(int, v), 0x01F0));
}

// ---------------------------------------------------------------------------
// K0: prep transposed bf16 weights + xnorm. grid 128 x 256.
// ---------------------------------------------------------------------------
__global__ __launch_bounds__(256) void k0_prep(
        const float* __restrict__ kvw2, const float* __restrict__ phxw1,
        const float* __restrict__ X, const float* __restrict__ xw,
        const float* __restrict__ qw1, const float* __restrict__ qw2,
        const float* __restrict__ kvw1,
        const float* __restrict__ phh1, const float* __restrict__ phh2,
        unsigned short* __restrict__ w2x, float* __restrict__ Xn4,
        unsigned short* __restrict__ qw1T, unsigned short* __restrict__ qw2T,
        unsigned short* __restrict__ kvw1T,
        unsigned short* __restrict__ phh1T, unsigned short* __restrict__ phh2T) {
    const int k = blockIdx.x;       // 0..127 : k-index and batch id
    const int T = threadIdx.x;
    if (T < 128) {
        w2x[T*PSTR + k] = bf16bits(kvw2[k*128 + T]);
    } else if (T < 192) {
        const int n2 = T - 128;
        float acc = 0.f;
        #pragma unroll 8
        for (int j = 0; j < 64; ++j)
            acc += kvw2[k*128 + 64 + j] * phxw1[j*64 + n2];
        w2x[(128 + n2)*PSTR + k] = bf16bits(acc);
    } else {
        const int L = T - 192;      // wave 3: xnorm for batch k
        const int n = k*64 + L;
        const float x0 = X[n*3+0], x1 = X[n*3+1], x2 = X[n*3+2];
        const float nm = sqrtf(x0*x0 + x1*x1 + x2*x2);
        const float mean = wsum(nm) * (1.0f/64.0f);
        const float sc = xw[0] * frcp(mean + 1e-5f);
        float4 o; o.x = x0*sc; o.y = x1*sc; o.z = x2*sc; o.w = 0.f;
        *(float4*)&Xn4[n*4] = o;
    }
    if (k < 64) {
        if (T < 128) kvw1T[T*WS72 + k] = bf16bits(kvw1[(1+k)*128 + T]);
    } else {
        const int kk = k - 64;
        if (T < 64)       qw1T[T*WS72 + kk]        = bf16bits(qw1[kk*64 + T]);
        else if (T < 128) qw2T[(T-64)*WS72 + kk]   = bf16bits(qw2[kk*64 + (T-64)]);
        else if (T < 192) phh1T[(T-128)*WS72 + kk] = bf16bits(phh1[kk*64 + (T-128)]);
        else              phh2T[(T-192)*WS72 + kk] = bf16bits(phh2[kk*64 + (T-192)]);
    }
}

// ---------------------------------------------------------------------------
// K2 (MFMA): single-wave 16-node tiles, role-split blocks. grid 1024 x 64.
// ---------------------------------------------------------------------------
__global__ __launch_bounds__(64) void k2_node(
        const float* __restrict__ H,
        const unsigned short* __restrict__ wbase,   // qw1T|qw2T|kvw1T
        const float* __restrict__ qnw, const float* __restrict__ qnb,
        float* __restrict__ Qn, unsigned short* __restrict__ Ptb) {
    const int tile = blockIdx.x >> 1, role = blockIdx.x & 1;
    const int nb = tile * 16;
    const int L = threadIdx.x, q = L >> 4, m = L & 15;
    __shared__ __align__(16) unsigned short zb[16*WS72];

    bf16x8 hf[2];
    #pragma unroll
    for (int ks = 0; ks < 2; ++ks) {
        float v[8];
        *(float4*)&v[0] = *(const float4*)&H[(size_t)(nb + m)*64 + ks*32 + q*8];
        *(float4*)&v[4] = *(const float4*)&H[(size_t)(nb + m)*64 + ks*32 + q*8 + 4];
        hf[ks] = to_bf16x8(v);
    }

    f32x4 acc[4];
    if (role == 1) {
        const unsigned short* kvw1T = wbase + 128*WS72;
        #pragma unroll
        for (int ph = 0; ph < 2; ++ph) {
            #pragma unroll
            for (int ct = 0; ct < 4; ++ct) acc[ct] = (f32x4){0.f,0.f,0.f,0.f};
            #pragma unroll
            for (int ks = 0; ks < 2; ++ks)
                #pragma unroll
                for (int ct = 0; ct < 4; ++ct) {
                    const bf16x8 b = *(const bf16x8*)&kvw1T[(ph*64 + ct*16 + m)*WS72 + ks*32 + q*8];
                    acc[ct] = __builtin_amdgcn_mfma_f32_16x16x32_bf16(hf[ks], b, acc[ct], 0, 0, 0);
                }
            #pragma unroll
            for (int ct = 0; ct < 4; ++ct)
                #pragma unroll
                for (int r = 0; r < 4; ++r)
                    Ptb[(size_t)(nb + q*4 + r)*PSTR + ph*64 + ct*16 + m]
                        = bf16bits(acc[ct][r]);
        }
        return;
    }

    // role 0: GEMM1 Z = silu(H@qw1)
    #pragma unroll
    for (int ct = 0; ct < 4; ++ct) acc[ct] = (f32x4){0.f,0.f,0.f,0.f};
    #pragma unroll
    for (int ks = 0; ks < 2; ++ks)
        #pragma unroll
        for (int ct = 0; ct < 4; ++ct) {
            const bf16x8 b = *(const bf16x8*)&wbase[(ct*16 + m)*WS72 + ks*32 + q*8];
            acc[ct] = __builtin_amdgcn_mfma_f32_16x16x32_bf16(hf[ks], b, acc[ct], 0, 0, 0);
        }
    #pragma unroll
    for (int ct = 0; ct < 4; ++ct)
        #pragma unroll
        for (int r = 0; r < 4; ++r)
            zb[(q*4 + r)*WS72 + ct*16 + m] = bf16bits(silu_f(acc[ct][r]));

    bf16x8 zf[2];
    #pragma unroll
    for (int ks = 0; ks < 2; ++ks)
        zf[ks] = *(const bf16x8*)&zb[m*WS72 + ks*32 + q*8];
    const unsigned short* qw2T = wbase + 64*WS72;
    #pragma unroll
    for (int ct = 0; ct < 4; ++ct) acc[ct] = (f32x4){0.f,0.f,0.f,0.f};
    #pragma unroll
    for (int ks = 0; ks < 2; ++ks)
        #pragma unroll
        for (int ct = 0; ct < 4; ++ct) {
            const bf16x8 b = *(const bf16x8*)&qw2T[(ct*16 + m)*WS72 + ks*32 + q*8];
            acc[ct] = __builtin_amdgcn_mfma_f32_16x16x32_bf16(zf[ks], b, acc[ct], 0, 0, 0);
        }
    float qnwv[4], qnbv[4];
    #pragma unroll
    for (int ct = 0; ct < 4; ++ct) { qnwv[ct] = qnw[ct*16+m]; qnbv[ct] = qnb[ct*16+m]; }
    #pragma unroll
    for (int r = 0; r < 4; ++r) {
        float s1 = 0.f, s2 = 0.f;
        #pragma unroll
        for (int ct = 0; ct < 4; ++ct) {
            const float z = acc[ct][r];
            s1 += z; s2 = fmaf(z, z, s2);
        }
        #pragma unroll
        for (int sh = 1; sh < 16; sh <<= 1) {
            s1 += __shfl_xor(s1, sh, 64);
            s2 += __shfl_xor(s2, sh, 64);
        }
        const float mu = s1 * (1.0f/64.0f);
        const float rstd = rsqrtf(s2 * (1.0f/64.0f) - mu*mu + 1e-5f);
        const int row = nb + q*4 + r;
        #pragma unroll
        for (int ct = 0; ct < 4; ++ct)
            Qn[(size_t)row*64 + ct*16 + m] = (acc[ct][r] - mu)*rstd*qnwv[ct] + qnbv[ct];
    }
}

// ---------------------------------------------------------------------------
// K3: fused edge pipeline + H-MLP epilogue. Block = (graph, 8 dsts),
// 256 thr / 2 pairs; wave half h owns src rows [32h,32h+32).
// Config = R9-clean (256,4 / K|V in LDS / G global / incremental ct)
// + R10's DPP softmax and DPP xa epilogue (no accv hoist).
// Register-budget frontier (measured): (256,3)=84 VGPR clean,
// (256,4)=60 VGPR clean, (256,5)=spill, accv-hoist@(256,4)=spill.
// ---------------------------------------------------------------------------
__global__ __launch_bounds__(256, 4) void k3_edge(
        const float* __restrict__ Xn4, const float* __restrict__ Qn,
        const unsigned short* __restrict__ Ptb,
        const unsigned short* __restrict__ w2x,
        const float* __restrict__ kvw1,
        const float* __restrict__ knw, const float* __restrict__ knb,
        const float* __restrict__ pxw2,
        const unsigned short* __restrict__ phhT,   // phh1T|phh2T
        const float* __restrict__ phb1, const float* __restrict__ phb2,
        const float* __restrict__ H,
        float* __restrict__ Hout, float* __restrict__ Xout) {
    const int bid = blockIdx.x;
    const int g = bid >> 3, dgrp = bid & 7;
    const int T = threadIdx.x, w = T >> 6, L = T & 63;
    const int q = L >> 4, m = L & 15;
    const int pair = w >> 1, half = w & 1;

    __shared__ __align__(16) unsigned short sw2[128*PSTR];  // 34816 B (K|V)
    __shared__ __align__(16) float sxr[4][32][4];           // 2048 B
    __shared__ __align__(16) unsigned short sAb[8*WS72];    // 1152 B
    __shared__ float w0s[128];                              // 512 B
    __shared__ float knws[64], knbs[64], pxs[64];           // 768 B
    __shared__ float sred[2][2][2];
    __shared__ float sA[2][64];
    __shared__ float sX[2][4];

    // ---- staging (once per block) ----
    {
        const uint4* s1 = (const uint4*)w2x;
        uint4* d1 = (uint4*)sw2;
        #pragma unroll
        for (int it = 0; it < 9; ++it) {
            const int idx = T + 256*it;
            if (idx < 128*PSTR/8) d1[idx] = s1[idx];
        }
        if (T < 128) w0s[T] = kvw1[T];
        if (T < 64)            knws[T]       = knw[T];
        else if (T < 128)      knbs[T - 64]  = knb[T - 64];
        else if (T < 192)      pxs[T - 128]  = pxw2[T - 128];
    }
    __syncthreads();

    const unsigned short* PtG = Ptb + (size_t)g*64*PSTR;
    const unsigned short* Gw  = w2x + 128*PSTR;     // G-weight rows (global)
    const float mflag = (m == 15) ? 1.0f : 0.0f;

    #pragma unroll 1
    for (int i = 0; i < 4; ++i) {
        const int dql = i*2 + pair;         // 0..7 local dst
        const int dl  = dgrp*8 + dql;       // 0..63 in-graph dst
        const int d   = g*64 + dl;

        // ---- Qn for this dst (global, L2-hot) ----
        float qdv[4];
        #pragma unroll
        for (int ct = 0; ct < 4; ++ct)
            qdv[ct] = Qn[(size_t)d*64 + ct*16 + m];

        // ---- geometry for this wave's 32 src rows ----
        if (L < 32) {
            const int row = half*32 + L;
            const float4 xs  = *(const float4*)&Xn4[(g*64 + row)*4];
            const float4 xdv = *(const float4*)&Xn4[(g*64 + dl)*4];
            const float r0 = xs.x - xdv.x, r1 = xs.y - xdv.y, r2 = xs.z - xdv.z;
            const float rd = r0*r0 + r1*r1 + r2*r2;
            const float inv = frcp(1.0f + sqrtf(rd + 1e-8f));
            float4 o; o.x = r0*inv; o.y = r1*inv; o.z = r2*inv; o.w = rd;
            *(float4*)&sxr[w][L][0] = o;
        }
        asm volatile("s_waitcnt lgkmcnt(0)" ::: "memory");

        // ---- build t A-fragments (rows half*32 + rt*16 + m) ----
        bf16x8 af[2][4];
        float rdv[2];
        #pragma unroll
        for (int rt = 0; rt < 2; ++rt) rdv[rt] = sxr[w][rt*16 + m][3];
        #pragma unroll
        for (int ks = 0; ks < 4; ++ks) {
            float w0v[8];
            *(float4*)&w0v[0] = *(const float4*)&w0s[ks*32 + q*8];
            *(float4*)&w0v[4] = *(const float4*)&w0s[ks*32 + q*8 + 4];
            #pragma unroll
            for (int rt = 0; rt < 2; ++rt) {
                const int row = half*32 + rt*16 + m;
                const bf16x8 pb = *(const bf16x8*)&PtG[(size_t)row*PSTR + ks*32 + q*8];
                bf16x8 o;
                #pragma unroll
                for (int j = 0; j < 8; ++j) {
                    const float pf = (float)pb[j];
                    o[j] = (__bf16)silu_f(fmaf(rdv[rt], w0v[j], pf));
                }
                af[rt][ks] = o;
            }
        }

        // ---- K-pass: incremental ct, LN stats accumulate (LDS weights) ----
        float qdw[4], Sqdw = 0.f, Sqdb = 0.f;
        #pragma unroll
        for (int ct = 0; ct < 4; ++ct) {
            qdw[ct] = qdv[ct] * knws[ct*16 + m];
            Sqdw += qdw[ct];
            Sqdb += qdv[ct] * knbs[ct*16 + m];
        }
        Sqdw = row_sum16(Sqdw);
        Sqdb = row_sum16(Sqdb);

        float s1a[2][4], s2a[2][4], skqa[2][4];
        #pragma unroll
        for (int rt = 0; rt < 2; ++rt)
            #pragma unroll
            for (int r = 0; r < 4; ++r) { s1a[rt][r]=0.f; s2a[rt][r]=0.f; skqa[rt][r]=0.f; }

        #pragma unroll
        for (int ct = 0; ct < 4; ++ct) {
            f32x4 acc[2];
            acc[0] = (f32x4){0.f,0.f,0.f,0.f};
            acc[1] = (f32x4){0.f,0.f,0.f,0.f};
            #pragma unroll
            for (int ks = 0; ks < 4; ++ks) {
                const bf16x8 b = *(const bf16x8*)&sw2[(ct*16 + m)*PSTR + ks*32 + q*8];
                #pragma unroll
                for (int rt = 0; rt < 2; ++rt)
                    acc[rt] = __builtin_amdgcn_mfma_f32_16x16x32_bf16(
                                  af[rt][ks], b, acc[rt], 0, 0, 0);
            }
            #pragma unroll
            for (int rt = 0; rt < 2; ++rt)
                #pragma unroll
                for (int r = 0; r < 4; ++r) {
                    const float kv = acc[rt][r];
                    s1a[rt][r] += kv;
                    s2a[rt][r] = fmaf(kv, kv, s2a[rt][r]);
                    skqa[rt][r] = fmaf(kv, qdw[ct], skqa[rt][r]);
                }
        }

        float sc[2][4];
        #pragma unroll
        for (int rt = 0; rt < 2; ++rt)
            #pragma unroll
            for (int r = 0; r < 4; ++r) {
                const float s1 = row_sum16(s1a[rt][r]);
                const float s2 = row_sum16(s2a[rt][r]);
                const float skq = row_sum16(skqa[rt][r]);
                const float mu = s1 * (1.0f/64.0f);
                const float rstd = rsqrtf(s2 * (1.0f/64.0f) - mu*mu + 1e-5f);
                float scv = (rstd * (skq - mu*Sqdw) + Sqdb) * 0.125f;
                scv = bcast15(scv);
                const int row_g = half*32 + rt*16 + q*4 + r;
                sc[rt][r] = (row_g == dl) ? -1e30f : scv;
            }

        // ---- wave-local softmax stats via DPP ----
        float mloc = -1e30f;
        #pragma unroll
        for (int rt = 0; rt < 2; ++rt)
            #pragma unroll
            for (int r = 0; r < 4; ++r) mloc = fmaxf(mloc, sc[rt][r]);
        const float smx = readlane63(wave_max_dpp(mloc));
        float e8[2][4], ssum = 0.f;
        #pragma unroll
        for (int rt = 0; rt < 2; ++rt)
            #pragma unroll
            for (int r = 0; r < 4; ++r) {
                e8[rt][r] = __expf(sc[rt][r] - smx);
                ssum += e8[rt][r];
            }
        // rows duplicated over 16 m-lanes -> Sw = 16 * true sum (folded below)
        const float Sw = readlane63(wave_sum_dpp(ssum));
        if (L == 0) { sred[pair][half][0] = smx; sred[pair][half][1] = Sw; }
        __syncthreads();                                    // b1
        float al[2][4];
        {
            const float mo = sred[pair][half^1][0];
            const float So = sred[pair][half^1][1];
            const float M  = fmaxf(smx, mo);
            const float es = __expf(smx - M);
            const float eo = __expf(mo - M);
            const float alf = 16.0f * es * frcp(Sw*es + So*eo);
            #pragma unroll
            for (int rt = 0; rt < 2; ++rt)
                #pragma unroll
                for (int r = 0; r < 4; ++r) al[rt][r] = e8[rt][r] * alf;
        }

        // ---- V-pass: incremental ct (LDS weights rows 64..127) ----
        float p[4];
        #pragma unroll
        for (int ct = 0; ct < 4; ++ct) {
            f32x4 acc[2];
            acc[0] = (f32x4){0.f,0.f,0.f,0.f};
            acc[1] = (f32x4){0.f,0.f,0.f,0.f};
            #pragma unroll
            for (int ks = 0; ks < 4; ++ks) {
                const bf16x8 b = *(const bf16x8*)&sw2[(64 + ct*16 + m)*PSTR + ks*32 + q*8];
                #pragma unroll
                for (int rt = 0; rt < 2; ++rt)
                    acc[rt] = __builtin_amdgcn_mfma_f32_16x16x32_bf16(
                                  af[rt][ks], b, acc[rt], 0, 0, 0);
            }
            float pv = 0.f;
            #pragma unroll
            for (int rt = 0; rt < 2; ++rt)
                #pragma unroll
                for (int r = 0; r < 4; ++r)
                    pv = fmaf(al[rt][r], acc[rt][r], pv);
            pv += __shfl_xor(pv, 16, 64);
            pv += __shfl_xor(pv, 32, 64);
            p[ct] = pv;
        }

        // ---- G-pass: incremental ct (global weights), phsum accumulate ----
        float phsum[2][4];
        #pragma unroll
        for (int rt = 0; rt < 2; ++rt)
            #pragma unroll
            for (int r = 0; r < 4; ++r) phsum[rt][r] = 0.f;
        #pragma unroll
        for (int ct = 0; ct < 4; ++ct) {
            f32x4 acc[2];
            acc[0] = (f32x4){0.f,0.f,0.f,0.f};
            acc[1] = (f32x4){0.f,0.f,0.f,0.f};
            #pragma unroll
            for (int ks = 0; ks < 4; ++ks) {
                const bf16x8 b = *(const bf16x8*)&Gw[(size_t)(ct*16 + m)*PSTR + ks*32 + q*8];
                #pragma unroll
                for (int rt = 0; rt < 2; ++rt)
                    acc[rt] = __builtin_amdgcn_mfma_f32_16x16x32_bf16(
                                  af[rt][ks], b, acc[rt], 0, 0, 0);
            }
            const float px = pxs[ct*16 + m];
            #pragma unroll
            for (int rt = 0; rt < 2; ++rt)
                #pragma unroll
                for (int r = 0; r < 4; ++r)
                    phsum[rt][r] = fmaf(silu_f(al[rt][r] * acc[rt][r]), px, phsum[rt][r]);
        }

        // ---- phx epilogue + X partial (DPP) ----
        float xa0 = 0.f, xa1 = 0.f, xa2 = 0.f;
        #pragma unroll
        for (int rt = 0; rt < 2; ++rt)
            #pragma unroll
            for (int r = 0; r < 4; ++r) {
                const float ph = row_sum16(phsum[rt][r]) * mflag;
                const float4 xr = *(const float4*)&sxr[w][rt*16 + q*4 + r][0];
                xa0 = fmaf(ph, xr.x, xa0);
                xa1 = fmaf(ph, xr.y, xa1);
                xa2 = fmaf(ph, xr.z, xa2);
            }
        xa0 = dpp_add<0x142>(xa0); xa0 = dpp_add<0x143>(xa0);
        xa1 = dpp_add<0x142>(xa1); xa1 = dpp_add<0x143>(xa1);
        xa2 = dpp_add<0x142>(xa2); xa2 = dpp_add<0x143>(xa2);

        if (half == 1) {
            if (q == 0)
                #pragma unroll
                for (int ct = 0; ct < 4; ++ct) sA[pair][ct*16 + m] = p[ct];
            if (L == 63) {
                sX[pair][0] = xa0; sX[pair][1] = xa1; sX[pair][2] = xa2;
            }
        }
        __syncthreads();                                    // b2
        if (half == 0) {
            if (q == 0)
                #pragma unroll
                for (int ct = 0; ct < 4; ++ct)
                    sAb[dql*WS72 + ct*16 + m] =
                        bf16bits(p[ct] + sA[pair][ct*16 + m]);
            if (L == 63) {
                const float4 xdv = *(const float4*)&Xn4[(g*64 + dl)*4];
                Xout[(size_t)d*3 + 0] = xdv.x + xa0 + sX[pair][0];
                Xout[(size_t)d*3 + 1] = xdv.y + xa1 + sX[pair][1];
                Xout[(size_t)d*3 + 2] = xdv.z + xa2 + sX[pair][2];
            }
        }
    }

    // ---- fused k4: H_out MLP for this block's 8 dsts (wave 0 only) ----
    __syncthreads();
    if (w == 0) {
        const int mr = m & 7;
        const size_t nbase = (size_t)g*64 + dgrp*8;

        bf16x8 uf[2];
        #pragma unroll
        for (int ks = 0; ks < 2; ++ks) {
            const bf16x8 a8 = *(const bf16x8*)&sAb[mr*WS72 + ks*32 + q*8];
            float h[8], v[8];
            *(float4*)&h[0] = *(const float4*)&H[(nbase + mr)*64 + ks*32 + q*8];
            *(float4*)&h[4] = *(const float4*)&H[(nbase + mr)*64 + ks*32 + q*8 + 4];
            #pragma unroll
            for (int j = 0; j < 8; ++j) {
                const float a = (float)a8[j];
                v[j] = a * a * h[j];
            }
            uf[ks] = to_bf16x8(v);
        }

        f32x4 acc[4];
        #pragma unroll
        for (int ct = 0; ct < 4; ++ct) acc[ct] = (f32x4){0.f,0.f,0.f,0.f};
        #pragma unroll
        for (int ks = 0; ks < 2; ++ks)
            #pragma unroll
            for (int ct = 0; ct < 4; ++ct) {
                const bf16x8 b = *(const bf16x8*)&phhT[(ct*16 + m)*WS72 + ks*32 + q*8];
                acc[ct] = __builtin_amdgcn_mfma_f32_16x16x32_bf16(uf[ks], b, acc[ct], 0, 0, 0);
            }
        #pragma unroll
        for (int ct = 0; ct < 4; ++ct) {
            const float bv = phb1[ct*16 + m];
            #pragma unroll
            for (int r = 0; r < 4; ++r)
                if (q < 2)
                    sAb[(q*4 + r)*WS72 + ct*16 + m] = bf16bits(silu_f(acc[ct][r] + bv));
        }

        bf16x8 zf[2];
        #pragma unroll
        for (int ks = 0; ks < 2; ++ks)
            zf[ks] = *(const bf16x8*)&sAb[mr*WS72 + ks*32 + q*8];
        const unsigned short* phh2T = phhT + 64*WS72;
        #pragma unroll
        for (int ct = 0; ct < 4; ++ct) acc[ct] = (f32x4){0.f,0.f,0.f,0.f};
        #pragma unroll
        for (int ks = 0; ks < 2; ++ks)
            #pragma unroll
            for (int ct = 0; ct < 4; ++ct) {
                const bf16x8 b = *(const bf16x8*)&phh2T[(ct*16 + m)*WS72 + ks*32 + q*8];
                acc[ct] = __builtin_amdgcn_mfma_f32_16x16x32_bf16(zf[ks], b, acc[ct], 0, 0, 0);
            }
        #pragma unroll
        for (int ct = 0; ct < 4; ++ct) {
            const float bv = phb2[ct*16 + m];
            #pragma unroll
            for (int r = 0; r < 4; ++r)
                if (q < 2) {
                    const size_t idx = (nbase + q*4 + r)*64 + ct*16 + m;
                    Hout[idx] = H[idx] + acc[ct][r] + bv;
                }
        }
    }
}

// ---------------------------------------------------------------------------
extern "C" void kernel_launch(void* const* d_in, const int* in_sizes, int n_in,
                              void* d_out, int out_size, void* d_ws, size_t ws_size,
                              hipStream_t stream) {
    const float* X    = (const float*)d_in[1];
    const float* H    = (const float*)d_in[2];
    const float* xw   = (const float*)d_in[4];
    const float* qw1  = (const float*)d_in[5];
    const float* qw2  = (const float*)d_in[6];
    const float* kvw1 = (const float*)d_in[7];
    const float* kvw2 = (const float*)d_in[8];
    const float* qnw  = (const float*)d_in[9];
    const float* qnb  = (const float*)d_in[10];
    const float* knw  = (const float*)d_in[11];
    const float* knb  = (const float*)d_in[12];
    const float* pxw1 = (const float*)d_in[13];
    const float* pxw2 = (const float*)d_in[14];
    const float* phw1 = (const float*)d_in[15];
    const float* phb1 = (const float*)d_in[16];
    const float* phw2 = (const float*)d_in[17];
    const float* phb2 = (const float*)d_in[18];

    float* out = (float*)d_out;
    char*  ws  = (char*)d_ws;

    size_t off = 0;
    float* Xn4 = (float*)(ws + off);          off += (size_t)NTOT*4*4;
    float* Qn  = (float*)(ws + off);          off += (size_t)NTOT*64*4;
    unsigned short* Ptb = (unsigned short*)(ws + off); off += (size_t)NTOT*PSTR*2;
    unsigned short* w2x   = (unsigned short*)(ws + off); off += (size_t)192*PSTR*2;
    // k2 weights contiguous: qw1T | qw2T | kvw1T  (256 rows x WS72)
    unsigned short* qw1T  = (unsigned short*)(ws + off); off += (size_t)64*WS72*2;
    unsigned short* qw2T  = (unsigned short*)(ws + off); off += (size_t)64*WS72*2;
    unsigned short* kvw1T = (unsigned short*)(ws + off); off += (size_t)128*WS72*2;
    // k3 H-MLP weights contiguous: phh1T | phh2T  (128 rows x WS72)
    unsigned short* phh1T = (unsigned short*)(ws + off); off += (size_t)64*WS72*2;
    unsigned short* phh2T = (unsigned short*)(ws + off); off += (size_t)64*WS72*2;

    k0_prep<<<128, 256, 0, stream>>>(kvw2, pxw1, X, xw, qw1, qw2, kvw1,
                                     phw1, phw2, w2x, Xn4,
                                     qw1T, qw2T, kvw1T, phh1T, phh2T);
    k2_node<<<1024, 64, 0, stream>>>(H, qw1T, qnw, qnb, Qn, Ptb);
    k3_edge<<<1024, 256, 0, stream>>>(Xn4, Qn, Ptb, w2x, kvw1, knw, knb,
                                      pxw2, phh1T, phb1, phb2, H,
                                      out + NTOT*3, out);
}